// Round 10
// baseline (5883.662 us; speedup 1.0000x reference)
//
#include <hip/hip_runtime.h>
#include <hip/hip_bf16.h>

#define N_BATCH 8
#define N_CH    16
#define N_SMP   480000
#define N_EARS  2
#define N_TAP   2048

#define U16     129                   // K-steps of 16: K = 2064 covers taps exactly
#define ROWS    256                   // q-rows per block (4 waves x 2 msubs x 32)
#define N_QROWS (N_SMP / 16)          // 30000
#define QB_PER_B ((N_QROWS + ROWS - 1) / ROWS)   // 118
#define XS_LEN  6400                  // bf16 elems per buffer (6160 real + pad)
#define NF4     (XS_LEN / 4)          // 1600 float4 staging slots
#define BLK     256
#define BQD     6                     // B prefetch depth in u-steps (= 3 kt32, round-3-proven slack)
#define WD      34                    // A-window depth: reuse distance 32 + 2 slack

typedef __bf16 bf16x8 __attribute__((ext_vector_type(8)));
typedef float  f32x16 __attribute__((ext_vector_type(16)));

// ---------------------------------------------------------------------------
// Prep: pack filters into 32x32x16 MFMA-B-fragment order, BOTH EARS in one
// fragment (N=32: cols 0-15 ear 0, 16-31 ear 1).
// B[k][n] = h[e=n>>4][c][2048 - k + (n&15)], k = u*16 + (lane>>5)*8 + j.
// Flat: (((c*U16 + u)*64 + lane)*8 + j -> 16B/lane, coalesced.
// ---------------------------------------------------------------------------
__global__ void build_bpk(const float* __restrict__ h, __bf16* __restrict__ bpk)
{
    const int idx = blockIdx.x * 256 + threadIdx.x;
    const int total = N_CH * U16 * 64 * 8;       // 1,056,768
    if (idx >= total) return;

    const int j    = idx & 7;
    const int lane = (idx >> 3) & 63;
    const int cu   = idx >> 9;                   // c*U16 + u
    const int u    = cu % U16;
    const int c    = cu / U16;

    const int n   = lane & 31;
    const int hi  = lane >> 5;
    const int k   = u * 16 + hi * 8 + j;
    const int e   = n >> 4;
    const int pos = n & 15;
    const int tap = 2048 - k + pos;

    float val = (tap >= 0 && tap < N_TAP) ? h[((long)e * N_CH + c) * N_TAP + tap] : 0.0f;
    bpk[idx] = (__bf16)val;
}

// ---------------------------------------------------------------------------
// Barrier with LGKM-only drain (round-8, verified +2%): BQ-prime global loads
// are register-destined (wave-local) and legally stay in flight across the
// barrier; only the LDS staging writes (lgkm) must drain.
// ---------------------------------------------------------------------------
__device__ __forceinline__ void barrier_lgkm_only()
{
    asm volatile("s_waitcnt lgkmcnt(0)" ::: "memory");
    __builtin_amdgcn_sched_barrier(0);
    __builtin_amdgcn_s_barrier();
}

// ---------------------------------------------------------------------------
// Main GEMM -- round-8 champion schedule ported to v_mfma_f32_32x32x16_bf16:
//   * ceiling 2075 -> 2382 TF (+15%); MFMA instr count per K-tile-32: 8 -> 4
//   * N=32 packs BOTH ears in one MFMA -> single B stream (BQ[6] = 24 regs,
//     same as old dual BQ0/BQ1[3]); acc = 2 msubs x f32x16 = 32 regs (same)
//   * A-window: rolling WIN[34] (136 regs ~ old W[4][8]'s 128). Invariant:
//     a0 = WIN[u%34] = g(u) (msub 0), a1 = WIN[(u+32)%34] = g(u+32) (msub 1,
//     slot refilled at u-2 -> 2-step slack); refill WIN[u%34] <- g(u+34).
//     One ds_read_b128 per u = 30 B/cyc/CU << 85 LDS ceiling. Each fragment
//     read once, used twice (read-per-use would be LDS-bound -- checked).
//   * K granule 16 -> exactly 129 steps, no tail case.
//   * kept verbatim: cooperative double-buffer staging, lgkm-only barrier,
//     setprio around MFMA cluster, staging issue/write at fixed u.
// g(j) = xs[a2 + 16j], a2 = wv*1024 + 16*(lane&31) + 8*(lane>>5); msub m adds
// 512 = 32 steps (folded into a1's +32). Max LDS offset 6175 < 6400 pad. A
// layout: row = lane&31, k = (lane>>5)*8+j (mirror of verified 16x16 usage);
// C/D: col = lane&31, row = (reg&3)+8*(reg>>2)+4*(lane>>5) [m74/m101].
// ---------------------------------------------------------------------------
__global__ __launch_bounds__(BLK, 2)
void hoa_bin_gemm(const float* __restrict__ hoa,
                  const __bf16* __restrict__ bpk,
                  float* __restrict__ out)
{
    __shared__ __align__(16) __bf16 xs[2][XS_LEN];

    const int qb   = blockIdx.x;          // 0..117
    const int b    = blockIdx.y;          // 0..7
    const int tid  = threadIdx.x;
    const int lane = tid & 63;
    const int wv   = tid >> 6;            // wave 0..3
    const int l31  = lane & 31;
    const int l5   = lane >> 5;

    const int q0 = qb * ROWS;
    const int t0 = 16 * q0 - 2048;        // sample index of xs[.][0]

    const int a2 = wv * 1024 + 16 * l31 + 8 * l5;   // elem offset of g(0)

    const float* xb = hoa + (long)b * N_CH * N_SMP;

    f32x16 acc[2] = {};                   // [msub]; cols = 2 ears x 16

    // ---- prologue: stage channel 0 into xs[0] (round-8 verbatim) ----
    {
        float4 v[7];
        #pragma unroll
        for (int k = 0; k < 7; ++k) {
            const int i4 = tid + k * BLK;
            const int t  = t0 + 4 * i4;
            float4 w = {0.f, 0.f, 0.f, 0.f};
            if (i4 < NF4 && t >= 0 && t <= N_SMP - 4) w = *(const float4*)(xb + t);
            v[k] = w;
        }
        #pragma unroll
        for (int k = 0; k < 7; ++k) {
            const int i4 = tid + k * BLK;
            if (i4 < NF4) {
                union { __bf16 hh[4]; uint2 u; } pk;
                pk.hh[0] = (__bf16)v[k].x; pk.hh[1] = (__bf16)v[k].y;
                pk.hh[2] = (__bf16)v[k].z; pk.hh[3] = (__bf16)v[k].w;
                *(uint2*)(&xs[0][4 * i4]) = pk.u;
            }
        }
    }

    for (int c = 0; c < N_CH; ++c) {
        const __bf16* bp = bpk + (long)c * (U16 * 512) + lane * 8;

        // ---- prime B queue (depth BQD u-steps) BEFORE barrier ----
        bf16x8 BQ[BQD];
        #pragma unroll
        for (int d = 0; d < BQD; ++d)
            BQ[d] = *(const bf16x8*)(bp + d * 512);

        barrier_lgkm_only();   // xs[c&1] staged; previous readers done

        const __bf16* xw = &xs[c & 1][0];

        // ---- preload A window; u=0's operands (slots 0, 32) first ----
        bf16x8 WIN[WD];
        WIN[0]  = *(const bf16x8*)(xw + a2);
        WIN[32] = *(const bf16x8*)(xw + a2 + 16 * 32);
        #pragma unroll
        for (int jj = 1; jj < WD; ++jj)
            if (jj != 32)
                WIN[jj] = *(const bf16x8*)(xw + a2 + 16 * jj);

        float4 sreg[7];    // staging regs — live u 16..96 only

        // ---- 129 u-steps, fully unrolled ----
        #pragma unroll
        for (int u = 0; u < U16; ++u) {
            const int d = u % BQD;
            bf16x8 bb = BQ[d];
            const int v = (u + BQD <= U16 - 1) ? u + BQD : U16 - 1;   // compile-time
            BQ[d] = *(const bf16x8*)(bp + v * 512);

            bf16x8 a0 = WIN[u % WD];
            bf16x8 a1 = WIN[(u + 32) % WD];
            // refill retired slot with g(u+34) (consumed as a1 at u+2,
            // as a0 at u+34; beyond-range refills land in pad, max 6175)
            WIN[u % WD] = *(const bf16x8*)(xw + a2 + 16 * (u + WD));

            __builtin_amdgcn_s_setprio(1);
            acc[0] = __builtin_amdgcn_mfma_f32_32x32x16_bf16(a0, bb, acc[0], 0, 0, 0);
            acc[1] = __builtin_amdgcn_mfma_f32_32x32x16_bf16(a1, bb, acc[1], 0, 0, 0);
            __builtin_amdgcn_s_setprio(0);

            // staging pipeline for channel c+1 (fixed-u, compile-time)
            if (u == 16 && c + 1 < N_CH) {
                const float* xc = xb + (long)(c + 1) * N_SMP;
                #pragma unroll
                for (int k = 0; k < 7; ++k) {
                    const int i4 = tid + k * BLK;
                    const int t  = t0 + 4 * i4;
                    float4 w = {0.f, 0.f, 0.f, 0.f};
                    if (i4 < NF4 && t >= 0 && t <= N_SMP - 4) w = *(const float4*)(xc + t);
                    sreg[k] = w;
                }
            }
            if (u == 96 && c + 1 < N_CH) {
                __bf16* xd = &xs[(c + 1) & 1][0];
                #pragma unroll
                for (int k = 0; k < 7; ++k) {
                    const int i4 = tid + k * BLK;
                    if (i4 < NF4) {
                        union { __bf16 hh[4]; uint2 u2; } pk;
                        pk.hh[0] = (__bf16)sreg[k].x; pk.hh[1] = (__bf16)sreg[k].y;
                        pk.hh[2] = (__bf16)sreg[k].z; pk.hh[3] = (__bf16)sreg[k].w;
                        *(uint2*)(&xd[4 * i4]) = pk.u2;
                    }
                }
            }
        }
    }

    // ---- epilogue: 32x32 C/D layout col=lane&31, row=(rg&3)+8*(rg>>2)+4*hi ----
    const long ob  = (long)b * N_EARS * N_SMP;
    const int  e   = (lane >> 4) & 1;     // col n = lane&31: ear = n>>4
    const int  pos = lane & 15;           // sample-pos = n&15
    #pragma unroll
    for (int m = 0; m < 2; ++m) {
        #pragma unroll
        for (int rg = 0; rg < 16; ++rg) {
            const int row = (rg & 3) + 8 * (rg >> 2) + 4 * l5;
            const int q   = q0 + wv * 64 + 32 * m + row;
            if (q < N_QROWS)
                out[ob + (long)e * N_SMP + 16 * q + pos] = acc[m][rg];
        }
    }
}

// ---------------------------------------------------------------------------
extern "C" void kernel_launch(void* const* d_in, const int* in_sizes, int n_in,
                              void* d_out, int out_size, void* d_ws, size_t ws_size,
                              hipStream_t stream)
{
    const float* hoa = (const float*)d_in[0];   // [8,16,480000] fp32
    const float* h   = (const float*)d_in[1];   // [2,16,2048]  fp32
    float* out       = (float*)d_out;           // [8,2,480000] fp32
    __bf16* bpk      = (__bf16*)d_ws;           // 2,113,536 B filter pack

    const int total_bpk = N_CH * U16 * 64 * 8;              // 1,056,768
    build_bpk<<<(total_bpk + 255) / 256, 256, 0, stream>>>(h, bpk);

    dim3 grid(QB_PER_B, N_BATCH);
    hoa_bin_gemm<<<grid, BLK, 0, stream>>>(hoa, bpk, out);
}